// Round 1
// baseline (1359.858 us; speedup 1.0000x reference)
//
#include <hip/hip_runtime.h>

#define NN 100000
#define EE 1600000
#define GG 256
#define EPS 1e-5f
#define SCAN_BLOCKS ((NN + 255) / 256)  // 391

// ---------- graph structure ----------
__global__ void k_hist(const int* __restrict__ ei, int* __restrict__ deg) {
  int e = blockIdx.x * 256 + threadIdx.x;
  if (e < EE) atomicAdd(&deg[ei[EE + e]], 1);
}

__global__ void k_dinv(const int* __restrict__ deg, float* __restrict__ dinv) {
  int n = blockIdx.x * 256 + threadIdx.x;
  if (n < NN) dinv[n] = rsqrtf((float)deg[n] + 1.0f);
}

__global__ void k_scan1(const int* __restrict__ deg, int* __restrict__ row,
                        int* __restrict__ sums) {
  __shared__ int sh[256];
  int tid = threadIdx.x;
  int i = blockIdx.x * 256 + tid;
  int v = (i < NN) ? deg[i] : 0;
  sh[tid] = v;
  __syncthreads();
  for (int off = 1; off < 256; off <<= 1) {
    int add = (tid >= off) ? sh[tid - off] : 0;
    __syncthreads();
    sh[tid] += add;
    __syncthreads();
  }
  if (i < NN) row[i] = sh[tid] - v;            // exclusive within block
  if (tid == 255) sums[blockIdx.x] = sh[255];  // block total
}

__global__ void k_scan2(int* __restrict__ sums) {  // 1 block, 512 threads
  __shared__ int sh[512];
  int t = threadIdx.x;
  int v = (t < SCAN_BLOCKS) ? sums[t] : 0;
  sh[t] = v;
  __syncthreads();
  for (int off = 1; off < 512; off <<= 1) {
    int add = (t >= off) ? sh[t - off] : 0;
    __syncthreads();
    sh[t] += add;
    __syncthreads();
  }
  if (t < SCAN_BLOCKS) sums[t] = sh[t] - v;  // exclusive block offsets
}

__global__ void k_scan3(int* __restrict__ row, const int* __restrict__ sums,
                        int* __restrict__ fill) {
  int i = blockIdx.x * 256 + threadIdx.x;
  if (i < NN) {
    int r = row[i] + sums[i >> 8];
    row[i] = r;
    fill[i] = r;  // fill pointer for scatter pass
  }
  if (i == 0) row[NN] = EE;
}

__global__ void k_scatter(const int* __restrict__ ei, int* __restrict__ fill,
                          int* __restrict__ csr) {
  int e = blockIdx.x * 256 + threadIdx.x;
  if (e < EE) {
    int slot = atomicAdd(&fill[ei[EE + e]], 1);
    csr[slot] = ei[e];
  }
}

// ---------- per-layer compute ----------
// h'[n,c] = (x[n,:] @ W[:,c]) * dinv[n]
template <int K>
__global__ void k_mm(const float* __restrict__ x, const float* __restrict__ W,
                     const float* __restrict__ dinv, float* __restrict__ out) {
  int t = blockIdx.x * 256 + threadIdx.x;
  int n = t >> 6, c = t & 63;
  if (n >= NN) return;
  const float* xr = x + (size_t)n * K;
  float acc = 0.f;
#pragma unroll
  for (int k = 0; k < K; ++k) acc = fmaf(xr[k], W[k * 64 + c], acc);
  out[(size_t)n * 64 + c] = acc * dinv[n];
}

// out[n,c] = relu( ((h'[n,c] + sum_{s in in(n)} h'[s,c]) * dinv[n] + b[c]) * sc[c] + sh[c] )
__global__ void k_pull(const float* __restrict__ hp, const int* __restrict__ row,
                       const int* __restrict__ csr, const float* __restrict__ dinv,
                       const float* __restrict__ b, const float* __restrict__ gam,
                       const float* __restrict__ bet, const float* __restrict__ rm,
                       const float* __restrict__ rv, float* __restrict__ out) {
  int t = blockIdx.x * 256 + threadIdx.x;
  int n = t >> 6, lane = t & 63;
  if (n >= NN) return;
  int s0 = row[n], s1 = row[n + 1];
  float acc = hp[(size_t)n * 64 + lane];  // self-loop term (already *dinv[n])
  for (int i = s0; i < s1; ++i) {
    int s = csr[i];
    acc += hp[(size_t)s * 64 + lane];
  }
  float sc = gam[lane] * rsqrtf(rv[lane] + EPS);
  float sh = bet[lane] - rm[lane] * sc;
  float v = fmaf(fmaf(acc, dinv[n], b[lane]), sc, sh);
  out[(size_t)n * 64 + lane] = fmaxf(v, 0.f);
}

// layer-2 variant: fused global mean/max pooling instead of writing features
__global__ void k_pull_pool(const float* __restrict__ hp, const int* __restrict__ row,
                            const int* __restrict__ csr, const float* __restrict__ dinv,
                            const float* __restrict__ b, const float* __restrict__ gam,
                            const float* __restrict__ bet, const float* __restrict__ rm,
                            const float* __restrict__ rv, const int* __restrict__ bidx,
                            float* __restrict__ psum, unsigned* __restrict__ pmax,
                            float* __restrict__ cnt) {
  int t = blockIdx.x * 256 + threadIdx.x;
  int n = t >> 6, lane = t & 63;
  if (n >= NN) return;
  int s0 = row[n], s1 = row[n + 1];
  float acc = hp[(size_t)n * 64 + lane];
  for (int i = s0; i < s1; ++i) {
    int s = csr[i];
    acc += hp[(size_t)s * 64 + lane];
  }
  float sc = gam[lane] * rsqrtf(rv[lane] + EPS);
  float sh = bet[lane] - rm[lane] * sc;
  float v = fmaxf(fmaf(fmaf(acc, dinv[n], b[lane]), sc, sh), 0.f);
  int g = bidx[n];
  atomicAdd(&psum[g * 64 + lane], v);
  atomicMax(&pmax[g * 64 + lane], __float_as_uint(v));  // v >= 0: uint-bit order == float order
  if (lane == 0) atomicAdd(&cnt[g], 1.0f);
}

// ---------- graph-level MLP ----------
__global__ void k_mlp(const float* __restrict__ psum, const unsigned* __restrict__ pmax,
                      const float* __restrict__ cnt, const float* __restrict__ mW1,
                      const float* __restrict__ mb1, const float* __restrict__ mW2,
                      const float* __restrict__ mb2, const float* __restrict__ mW3,
                      const float* __restrict__ mb3, float* __restrict__ out) {
  __shared__ float xg[128], h1[32], h2[16];
  int g = blockIdx.x, t = threadIdx.x;  // 128 threads
  float c = fmaxf(cnt[g], 1.0f);
  if (t < 64)
    xg[t] = psum[g * 64 + t] / c;
  else
    xg[t] = __uint_as_float(pmax[g * 64 + (t - 64)]);
  __syncthreads();
  if (t < 32) {
    float a = mb1[t];
    for (int k = 0; k < 128; ++k) a = fmaf(xg[k], mW1[k * 32 + t], a);
    h1[t] = fmaxf(a, 0.f);
  }
  __syncthreads();
  if (t < 16) {
    float a = mb2[t];
    for (int k = 0; k < 32; ++k) a = fmaf(h1[k], mW2[k * 16 + t], a);
    h2[t] = fmaxf(a, 0.f);
  }
  __syncthreads();
  if (t == 0) {
    float a = mb3[0];
    for (int k = 0; k < 16; ++k) a = fmaf(h2[k], mW3[k], a);
    out[g] = a;
  }
}

extern "C" void kernel_launch(void* const* d_in, const int* in_sizes, int n_in,
                              void* d_out, int out_size, void* d_ws, size_t ws_size,
                              hipStream_t stream) {
  const float* x = (const float*)d_in[0];
  const int* ei = (const int*)d_in[1];
  const int* bidx = (const int*)d_in[2];
  const float *W[3], *b[3], *gam[3], *bet[3], *rm[3], *rv[3];
  for (int l = 0; l < 3; ++l) {
    W[l] = (const float*)d_in[3 + 6 * l];
    b[l] = (const float*)d_in[4 + 6 * l];
    gam[l] = (const float*)d_in[5 + 6 * l];
    bet[l] = (const float*)d_in[6 + 6 * l];
    rm[l] = (const float*)d_in[7 + 6 * l];
    rv[l] = (const float*)d_in[8 + 6 * l];
  }
  const float* mW1 = (const float*)d_in[21];
  const float* mb1 = (const float*)d_in[22];
  const float* mW2 = (const float*)d_in[23];
  const float* mb2 = (const float*)d_in[24];
  const float* mW3 = (const float*)d_in[25];
  const float* mb3 = (const float*)d_in[26];
  float* out = (float*)d_out;

  char* ws = (char*)d_ws;
  size_t off = 0;
  auto alloc = [&](size_t bytes) {
    void* p = ws + off;
    off = (off + bytes + 1023) & ~(size_t)1023;
    return p;
  };
  float* dinv = (float*)alloc(NN * 4);
  int* row = (int*)alloc((NN + 1) * 4);
  int* fill = (int*)alloc(NN * 4);
  int* csr = (int*)alloc((size_t)EE * 4);
  int* sums = (int*)alloc(512 * 4);
  float* bufA = (float*)alloc((size_t)NN * 64 * 4);
  float* bufB = (float*)alloc((size_t)NN * 64 * 4);
  float* psum = (float*)alloc(GG * 64 * 4);
  unsigned* pmax = (unsigned*)alloc(GG * 64 * 4);
  float* cnt = (float*)alloc(GG * 4);

  hipMemsetAsync(fill, 0, NN * 4, stream);
  hipMemsetAsync(psum, 0, GG * 64 * 4, stream);
  hipMemsetAsync(pmax, 0, GG * 64 * 4, stream);
  hipMemsetAsync(cnt, 0, GG * 4, stream);

  int eb = (EE + 255) / 256;
  int nb = (NN + 255) / 256;
  int nb64 = (NN * 64 + 255) / 256;

  // graph structure (once, reused for all 3 layers)
  k_hist<<<eb, 256, 0, stream>>>(ei, fill);
  k_dinv<<<nb, 256, 0, stream>>>(fill, dinv);
  k_scan1<<<SCAN_BLOCKS, 256, 0, stream>>>(fill, row, sums);
  k_scan2<<<1, 512, 0, stream>>>(sums);
  k_scan3<<<nb, 256, 0, stream>>>(row, sums, fill);
  k_scatter<<<eb, 256, 0, stream>>>(ei, fill, csr);

  // layer 0 (in=3)
  k_mm<3><<<nb64, 256, 0, stream>>>(x, W[0], dinv, bufB);
  k_pull<<<nb64, 256, 0, stream>>>(bufB, row, csr, dinv, b[0], gam[0], bet[0], rm[0], rv[0], bufA);
  // layer 1
  k_mm<64><<<nb64, 256, 0, stream>>>(bufA, W[1], dinv, bufB);
  k_pull<<<nb64, 256, 0, stream>>>(bufB, row, csr, dinv, b[1], gam[1], bet[1], rm[1], rv[1], bufA);
  // layer 2 + fused pooling
  k_mm<64><<<nb64, 256, 0, stream>>>(bufA, W[2], dinv, bufB);
  k_pull_pool<<<nb64, 256, 0, stream>>>(bufB, row, csr, dinv, b[2], gam[2], bet[2], rm[2], rv[2],
                                        bidx, psum, pmax, cnt);
  // graph MLP
  k_mlp<<<GG, 128, 0, stream>>>(psum, pmax, cnt, mW1, mb1, mW2, mb2, mW3, mb3, out);
}

// Round 2
// 1011.221 us; speedup vs baseline: 1.3448x; 1.3448x over previous
//
#include <hip/hip_runtime.h>

#define NN 100000
#define EE 1600000
#define GG 256
#define EPS 1e-5f
#define SCAN_BLOCKS ((NN + 255) / 256)  // 391

// ---------- graph structure ----------
__global__ void k_hist(const int* __restrict__ ei, int* __restrict__ deg) {
  int e = blockIdx.x * 256 + threadIdx.x;
  if (e < EE) atomicAdd(&deg[ei[EE + e]], 1);
}

__global__ void k_dinv(const int* __restrict__ deg, float* __restrict__ dinv) {
  int n = blockIdx.x * 256 + threadIdx.x;
  if (n < NN) dinv[n] = rsqrtf((float)deg[n] + 1.0f);
}

__global__ void k_scan1(const int* __restrict__ deg, int* __restrict__ row,
                        int* __restrict__ sums) {
  __shared__ int sh[256];
  int tid = threadIdx.x;
  int i = blockIdx.x * 256 + tid;
  int v = (i < NN) ? deg[i] : 0;
  sh[tid] = v;
  __syncthreads();
  for (int off = 1; off < 256; off <<= 1) {
    int add = (tid >= off) ? sh[tid - off] : 0;
    __syncthreads();
    sh[tid] += add;
    __syncthreads();
  }
  if (i < NN) row[i] = sh[tid] - v;
  if (tid == 255) sums[blockIdx.x] = sh[255];
}

__global__ void k_scan2(int* __restrict__ sums) {  // 1 block, 512 threads
  __shared__ int sh[512];
  int t = threadIdx.x;
  int v = (t < SCAN_BLOCKS) ? sums[t] : 0;
  sh[t] = v;
  __syncthreads();
  for (int off = 1; off < 512; off <<= 1) {
    int add = (t >= off) ? sh[t - off] : 0;
    __syncthreads();
    sh[t] += add;
    __syncthreads();
  }
  if (t < SCAN_BLOCKS) sums[t] = sh[t] - v;
}

__global__ void k_scan3(int* __restrict__ row, const int* __restrict__ sums,
                        int* __restrict__ fill) {
  int i = blockIdx.x * 256 + threadIdx.x;
  if (i < NN) {
    int r = row[i] + sums[i >> 8];
    row[i] = r;
    fill[i] = r;
  }
  if (i == 0) row[NN] = EE;
}

__global__ void k_scatter(const int* __restrict__ ei, int* __restrict__ fill,
                          int* __restrict__ csr) {
  int e = blockIdx.x * 256 + threadIdx.x;
  if (e < EE) {
    int slot = atomicAdd(&fill[ei[EE + e]], 1);
    csr[slot] = ei[e];
  }
}

// ---------- layer 0 (3-channel, agg-before-matmul) ----------
// xd[n] = {x[n,0..2] * dinv[n], pad} as float4
__global__ void k_predinv(const float* __restrict__ x, const float* __restrict__ dinv,
                          float4* __restrict__ xd) {
  int n = blockIdx.x * 256 + threadIdx.x;
  if (n >= NN) return;
  float d = dinv[n];
  xd[n] = make_float4(x[n * 3] * d, x[n * 3 + 1] * d, x[n * 3 + 2] * d, 0.f);
}

// xt[n] = dinv[n] * (sum_{s in in(n)} xd[s] + xd[n])   [N,4]
__global__ void k_agg3(const float4* __restrict__ xd, const int* __restrict__ row,
                       const int* __restrict__ csr, const float* __restrict__ dinv,
                       float4* __restrict__ xt) {
  int n = blockIdx.x * 256 + threadIdx.x;
  if (n >= NN) return;
  int s0 = row[n], s1 = row[n + 1];
  float4 a = xd[n];
  float ax = a.x, ay = a.y, az = a.z;
  int i = s0;
  for (; i + 8 <= s1; i += 8) {
    int idx[8];
#pragma unroll
    for (int j = 0; j < 8; ++j) idx[j] = csr[i + j];
    float4 v[8];
#pragma unroll
    for (int j = 0; j < 8; ++j) v[j] = xd[idx[j]];
#pragma unroll
    for (int j = 0; j < 8; ++j) { ax += v[j].x; ay += v[j].y; az += v[j].z; }
  }
  for (; i < s1; ++i) {
    float4 v = xd[csr[i]];
    ax += v.x; ay += v.y; az += v.z;
  }
  float d = dinv[n];
  xt[n] = make_float4(ax * d, ay * d, az * d, 0.f);
}

// bufA[n,c] = relu(BN(xt[n,:3] @ W0[:,c] + b[c]))
__global__ void k_mm3bn(const float4* __restrict__ xt, const float* __restrict__ W,
                        const float* __restrict__ b, const float* __restrict__ gam,
                        const float* __restrict__ bet, const float* __restrict__ rm,
                        const float* __restrict__ rv, float* __restrict__ out) {
  int t = blockIdx.x * 256 + threadIdx.x;
  int n = t >> 6, c = t & 63;
  if (n >= NN) return;
  float4 xv = xt[n];
  float acc = b[c];
  acc = fmaf(xv.x, W[c], acc);
  acc = fmaf(xv.y, W[64 + c], acc);
  acc = fmaf(xv.z, W[128 + c], acc);
  float sc = gam[c] * rsqrtf(rv[c] + EPS);
  float sh = bet[c] - rm[c] * sc;
  out[(size_t)n * 64 + c] = fmaxf(fmaf(acc, sc, sh), 0.f);
}

// ---------- 64-ch matmul: h'[n,c] = (x[n,:] @ W[:,c]) * dinv[n] ----------
__global__ void k_mm64(const float* __restrict__ x, const float* __restrict__ W,
                       const float* __restrict__ dinv, float* __restrict__ out) {
  int t = blockIdx.x * 256 + threadIdx.x;
  int n = t >> 4, sub = t & 15;
  if (n >= NN) return;
  const float4* x4 = (const float4*)x;
  const float4* W4 = (const float4*)W;
  float4 acc = make_float4(0.f, 0.f, 0.f, 0.f);
#pragma unroll
  for (int j = 0; j < 16; ++j) {
    float4 xv = x4[(size_t)n * 16 + j];
    float4 w0 = W4[(4 * j + 0) * 16 + sub];
    float4 w1 = W4[(4 * j + 1) * 16 + sub];
    float4 w2 = W4[(4 * j + 2) * 16 + sub];
    float4 w3 = W4[(4 * j + 3) * 16 + sub];
    acc.x = fmaf(xv.x, w0.x, acc.x); acc.y = fmaf(xv.x, w0.y, acc.y);
    acc.z = fmaf(xv.x, w0.z, acc.z); acc.w = fmaf(xv.x, w0.w, acc.w);
    acc.x = fmaf(xv.y, w1.x, acc.x); acc.y = fmaf(xv.y, w1.y, acc.y);
    acc.z = fmaf(xv.y, w1.z, acc.z); acc.w = fmaf(xv.y, w1.w, acc.w);
    acc.x = fmaf(xv.z, w2.x, acc.x); acc.y = fmaf(xv.z, w2.y, acc.y);
    acc.z = fmaf(xv.z, w2.z, acc.z); acc.w = fmaf(xv.z, w2.w, acc.w);
    acc.x = fmaf(xv.w, w3.x, acc.x); acc.y = fmaf(xv.w, w3.y, acc.y);
    acc.z = fmaf(xv.w, w3.z, acc.z); acc.w = fmaf(xv.w, w3.w, acc.w);
  }
  float d = dinv[n];
  acc.x *= d; acc.y *= d; acc.z *= d; acc.w *= d;
  ((float4*)out)[(size_t)n * 16 + sub] = acc;
}

// ---------- pull + BN + ReLU (16 lanes/node, float4, 4x unroll) ----------
__device__ __forceinline__ float4 pull_acc(const float4* __restrict__ hp4,
                                           const int* __restrict__ row,
                                           const int* __restrict__ csr, int n, int sub) {
  int s0 = row[n], s1 = row[n + 1];
  float4 a = hp4[(size_t)n * 16 + sub];  // self-loop term (already *dinv[n])
  int i = s0;
  for (; i + 4 <= s1; i += 4) {
    int i0 = csr[i], i1 = csr[i + 1], i2 = csr[i + 2], i3 = csr[i + 3];
    float4 v0 = hp4[(size_t)i0 * 16 + sub];
    float4 v1 = hp4[(size_t)i1 * 16 + sub];
    float4 v2 = hp4[(size_t)i2 * 16 + sub];
    float4 v3 = hp4[(size_t)i3 * 16 + sub];
    a.x += v0.x + v1.x + v2.x + v3.x;
    a.y += v0.y + v1.y + v2.y + v3.y;
    a.z += v0.z + v1.z + v2.z + v3.z;
    a.w += v0.w + v1.w + v2.w + v3.w;
  }
  for (; i < s1; ++i) {
    float4 v = hp4[(size_t)csr[i] * 16 + sub];
    a.x += v.x; a.y += v.y; a.z += v.z; a.w += v.w;
  }
  return a;
}

__global__ void k_pull(const float* __restrict__ hp, const int* __restrict__ row,
                       const int* __restrict__ csr, const float* __restrict__ dinv,
                       const float* __restrict__ b, const float* __restrict__ gam,
                       const float* __restrict__ bet, const float* __restrict__ rm,
                       const float* __restrict__ rv, float* __restrict__ out) {
  int t = blockIdx.x * 256 + threadIdx.x;
  int n = t >> 4, sub = t & 15;
  if (n >= NN) return;
  float4 a = pull_acc((const float4*)hp, row, csr, n, sub);
  float4 bb = ((const float4*)b)[sub];
  float4 g4 = ((const float4*)gam)[sub];
  float4 be4 = ((const float4*)bet)[sub];
  float4 rm4 = ((const float4*)rm)[sub];
  float4 rv4 = ((const float4*)rv)[sub];
  float d = dinv[n];
  float scx = g4.x * rsqrtf(rv4.x + EPS), shx = be4.x - rm4.x * scx;
  float scy = g4.y * rsqrtf(rv4.y + EPS), shy = be4.y - rm4.y * scy;
  float scz = g4.z * rsqrtf(rv4.z + EPS), shz = be4.z - rm4.z * scz;
  float scw = g4.w * rsqrtf(rv4.w + EPS), shw = be4.w - rm4.w * scw;
  float4 o;
  o.x = fmaxf(fmaf(fmaf(a.x, d, bb.x), scx, shx), 0.f);
  o.y = fmaxf(fmaf(fmaf(a.y, d, bb.y), scy, shy), 0.f);
  o.z = fmaxf(fmaf(fmaf(a.z, d, bb.z), scz, shz), 0.f);
  o.w = fmaxf(fmaf(fmaf(a.w, d, bb.w), scw, shw), 0.f);
  ((float4*)out)[(size_t)n * 16 + sub] = o;
}

__global__ void k_pull_pool(const float* __restrict__ hp, const int* __restrict__ row,
                            const int* __restrict__ csr, const float* __restrict__ dinv,
                            const float* __restrict__ b, const float* __restrict__ gam,
                            const float* __restrict__ bet, const float* __restrict__ rm,
                            const float* __restrict__ rv, const int* __restrict__ bidx,
                            float* __restrict__ psum, unsigned* __restrict__ pmax,
                            float* __restrict__ cnt) {
  int t = blockIdx.x * 256 + threadIdx.x;
  int n = t >> 4, sub = t & 15;
  if (n >= NN) return;
  float4 a = pull_acc((const float4*)hp, row, csr, n, sub);
  float4 bb = ((const float4*)b)[sub];
  float4 g4 = ((const float4*)gam)[sub];
  float4 be4 = ((const float4*)bet)[sub];
  float4 rm4 = ((const float4*)rm)[sub];
  float4 rv4 = ((const float4*)rv)[sub];
  float d = dinv[n];
  float scx = g4.x * rsqrtf(rv4.x + EPS), shx = be4.x - rm4.x * scx;
  float scy = g4.y * rsqrtf(rv4.y + EPS), shy = be4.y - rm4.y * scy;
  float scz = g4.z * rsqrtf(rv4.z + EPS), shz = be4.z - rm4.z * scz;
  float scw = g4.w * rsqrtf(rv4.w + EPS), shw = be4.w - rm4.w * scw;
  float vx = fmaxf(fmaf(fmaf(a.x, d, bb.x), scx, shx), 0.f);
  float vy = fmaxf(fmaf(fmaf(a.y, d, bb.y), scy, shy), 0.f);
  float vz = fmaxf(fmaf(fmaf(a.z, d, bb.z), scz, shz), 0.f);
  float vw = fmaxf(fmaf(fmaf(a.w, d, bb.w), scw, shw), 0.f);
  int g = bidx[n];
  int c0 = g * 64 + sub * 4;
  atomicAdd(&psum[c0 + 0], vx);
  atomicAdd(&psum[c0 + 1], vy);
  atomicAdd(&psum[c0 + 2], vz);
  atomicAdd(&psum[c0 + 3], vw);
  atomicMax(&pmax[c0 + 0], __float_as_uint(vx));
  atomicMax(&pmax[c0 + 1], __float_as_uint(vy));
  atomicMax(&pmax[c0 + 2], __float_as_uint(vz));
  atomicMax(&pmax[c0 + 3], __float_as_uint(vw));
  if (sub == 0) atomicAdd(&cnt[g], 1.0f);
}

// ---------- graph-level MLP ----------
__global__ void k_mlp(const float* __restrict__ psum, const unsigned* __restrict__ pmax,
                      const float* __restrict__ cnt, const float* __restrict__ mW1,
                      const float* __restrict__ mb1, const float* __restrict__ mW2,
                      const float* __restrict__ mb2, const float* __restrict__ mW3,
                      const float* __restrict__ mb3, float* __restrict__ out) {
  __shared__ float xg[128], h1[32], h2[16];
  int g = blockIdx.x, t = threadIdx.x;  // 128 threads
  float c = fmaxf(cnt[g], 1.0f);
  if (t < 64)
    xg[t] = psum[g * 64 + t] / c;
  else
    xg[t] = __uint_as_float(pmax[g * 64 + (t - 64)]);
  __syncthreads();
  if (t < 32) {
    float a = mb1[t];
    for (int k = 0; k < 128; ++k) a = fmaf(xg[k], mW1[k * 32 + t], a);
    h1[t] = fmaxf(a, 0.f);
  }
  __syncthreads();
  if (t < 16) {
    float a = mb2[t];
    for (int k = 0; k < 32; ++k) a = fmaf(h1[k], mW2[k * 16 + t], a);
    h2[t] = fmaxf(a, 0.f);
  }
  __syncthreads();
  if (t == 0) {
    float a = mb3[0];
    for (int k = 0; k < 16; ++k) a = fmaf(h2[k], mW3[k], a);
    out[g] = a;
  }
}

extern "C" void kernel_launch(void* const* d_in, const int* in_sizes, int n_in,
                              void* d_out, int out_size, void* d_ws, size_t ws_size,
                              hipStream_t stream) {
  const float* x = (const float*)d_in[0];
  const int* ei = (const int*)d_in[1];
  const int* bidx = (const int*)d_in[2];
  const float *W[3], *b[3], *gam[3], *bet[3], *rm[3], *rv[3];
  for (int l = 0; l < 3; ++l) {
    W[l] = (const float*)d_in[3 + 6 * l];
    b[l] = (const float*)d_in[4 + 6 * l];
    gam[l] = (const float*)d_in[5 + 6 * l];
    bet[l] = (const float*)d_in[6 + 6 * l];
    rm[l] = (const float*)d_in[7 + 6 * l];
    rv[l] = (const float*)d_in[8 + 6 * l];
  }
  const float* mW1 = (const float*)d_in[21];
  const float* mb1 = (const float*)d_in[22];
  const float* mW2 = (const float*)d_in[23];
  const float* mb2 = (const float*)d_in[24];
  const float* mW3 = (const float*)d_in[25];
  const float* mb3 = (const float*)d_in[26];
  float* out = (float*)d_out;

  char* ws = (char*)d_ws;
  size_t off = 0;
  auto alloc = [&](size_t bytes) {
    void* p = ws + off;
    off = (off + bytes + 1023) & ~(size_t)1023;
    return p;
  };
  float* dinv = (float*)alloc(NN * 4);
  int* row = (int*)alloc((NN + 1) * 4);
  int* fill = (int*)alloc(NN * 4);
  int* csr = (int*)alloc((size_t)EE * 4);
  int* sums = (int*)alloc(512 * 4);
  float4* xd = (float4*)alloc((size_t)NN * 16);
  float4* xt = (float4*)alloc((size_t)NN * 16);
  float* bufA = (float*)alloc((size_t)NN * 64 * 4);
  float* bufB = (float*)alloc((size_t)NN * 64 * 4);
  float* psum = (float*)alloc(GG * 64 * 4);
  unsigned* pmax = (unsigned*)alloc(GG * 64 * 4);
  float* cnt = (float*)alloc(GG * 4);

  hipMemsetAsync(fill, 0, NN * 4, stream);
  hipMemsetAsync(psum, 0, GG * 64 * 4, stream);
  hipMemsetAsync(pmax, 0, GG * 64 * 4, stream);
  hipMemsetAsync(cnt, 0, GG * 4, stream);

  int eb = (EE + 255) / 256;
  int nb = (NN + 255) / 256;
  int nb16 = (NN * 16 + 255) / 256;
  int nb64 = (NN * 64 + 255) / 256;

  // graph structure (once, reused for all 3 layers)
  k_hist<<<eb, 256, 0, stream>>>(ei, fill);
  k_dinv<<<nb, 256, 0, stream>>>(fill, dinv);
  k_scan1<<<SCAN_BLOCKS, 256, 0, stream>>>(fill, row, sums);
  k_scan2<<<1, 512, 0, stream>>>(sums);
  k_scan3<<<nb, 256, 0, stream>>>(row, sums, fill);
  k_scatter<<<eb, 256, 0, stream>>>(ei, fill, csr);

  // layer 0: aggregate 3-ch input first (agg(xW) == agg(x)W), then matmul+BN+ReLU
  k_predinv<<<nb, 256, 0, stream>>>(x, dinv, xd);
  k_agg3<<<nb, 256, 0, stream>>>(xd, row, csr, dinv, xt);
  k_mm3bn<<<nb64, 256, 0, stream>>>(xt, W[0], b[0], gam[0], bet[0], rm[0], rv[0], bufA);
  // layer 1
  k_mm64<<<nb16, 256, 0, stream>>>(bufA, W[1], dinv, bufB);
  k_pull<<<nb16, 256, 0, stream>>>(bufB, row, csr, dinv, b[1], gam[1], bet[1], rm[1], rv[1], bufA);
  // layer 2 + fused pooling
  k_mm64<<<nb16, 256, 0, stream>>>(bufA, W[2], dinv, bufB);
  k_pull_pool<<<nb16, 256, 0, stream>>>(bufB, row, csr, dinv, b[2], gam[2], bet[2], rm[2], rv[2],
                                        bidx, psum, pmax, cnt);
  // graph MLP
  k_mlp<<<GG, 128, 0, stream>>>(psum, pmax, cnt, mW1, mb1, mW2, mb2, mW3, mb3, out);
}

// Round 3
// 556.323 us; speedup vs baseline: 2.4444x; 1.8177x over previous
//
#include <hip/hip_runtime.h>

#define NN 100000
#define EE 1600000
#define GG 256
#define EPS 1e-5f
#define SCAN_BLOCKS ((NN + 255) / 256)  // 391

// ---------- graph structure ----------
__global__ void k_hist(const int* __restrict__ ei, int* __restrict__ deg) {
  int e = blockIdx.x * 256 + threadIdx.x;
  if (e < EE) atomicAdd(&deg[ei[EE + e]], 1);
}

__global__ void k_dinv(const int* __restrict__ deg, float* __restrict__ dinv) {
  int n = blockIdx.x * 256 + threadIdx.x;
  if (n < NN) dinv[n] = rsqrtf((float)deg[n] + 1.0f);
}

__global__ void k_scan1(const int* __restrict__ deg, int* __restrict__ row,
                        int* __restrict__ sums) {
  __shared__ int sh[256];
  int tid = threadIdx.x;
  int i = blockIdx.x * 256 + tid;
  int v = (i < NN) ? deg[i] : 0;
  sh[tid] = v;
  __syncthreads();
  for (int off = 1; off < 256; off <<= 1) {
    int add = (tid >= off) ? sh[tid - off] : 0;
    __syncthreads();
    sh[tid] += add;
    __syncthreads();
  }
  if (i < NN) row[i] = sh[tid] - v;
  if (tid == 255) sums[blockIdx.x] = sh[255];
}

__global__ void k_scan2(int* __restrict__ sums) {  // 1 block, 512 threads
  __shared__ int sh[512];
  int t = threadIdx.x;
  int v = (t < SCAN_BLOCKS) ? sums[t] : 0;
  sh[t] = v;
  __syncthreads();
  for (int off = 1; off < 512; off <<= 1) {
    int add = (t >= off) ? sh[t - off] : 0;
    __syncthreads();
    sh[t] += add;
    __syncthreads();
  }
  if (t < SCAN_BLOCKS) sums[t] = sh[t] - v;
}

__global__ void k_scan3(int* __restrict__ row, const int* __restrict__ sums,
                        int* __restrict__ fill) {
  int i = blockIdx.x * 256 + threadIdx.x;
  if (i < NN) {
    int r = row[i] + sums[i >> 8];
    row[i] = r;
    fill[i] = r;
  }
  if (i == 0) row[NN] = EE;
}

__global__ void k_scatter(const int* __restrict__ ei, int* __restrict__ fill,
                          int* __restrict__ csr) {
  int e = blockIdx.x * 256 + threadIdx.x;
  if (e < EE) {
    int slot = atomicAdd(&fill[ei[EE + e]], 1);
    csr[slot] = ei[e];
  }
}

// ---------- layer 0 (3-channel, agg-before-matmul) ----------
__global__ void k_predinv(const float* __restrict__ x, const float* __restrict__ dinv,
                          float4* __restrict__ xd) {
  int n = blockIdx.x * 256 + threadIdx.x;
  if (n >= NN) return;
  float d = dinv[n];
  xd[n] = make_float4(x[n * 3] * d, x[n * 3 + 1] * d, x[n * 3 + 2] * d, 0.f);
}

__global__ void k_agg3(const float4* __restrict__ xd, const int* __restrict__ row,
                       const int* __restrict__ csr, const float* __restrict__ dinv,
                       float4* __restrict__ xt) {
  int n = blockIdx.x * 256 + threadIdx.x;
  if (n >= NN) return;
  int s0 = row[n], s1 = row[n + 1];
  float4 a = xd[n];
  float ax = a.x, ay = a.y, az = a.z;
  int i = s0;
  for (; i + 8 <= s1; i += 8) {
    int idx[8];
#pragma unroll
    for (int j = 0; j < 8; ++j) idx[j] = csr[i + j];
    float4 v[8];
#pragma unroll
    for (int j = 0; j < 8; ++j) v[j] = xd[idx[j]];
#pragma unroll
    for (int j = 0; j < 8; ++j) { ax += v[j].x; ay += v[j].y; az += v[j].z; }
  }
  for (; i < s1; ++i) {
    float4 v = xd[csr[i]];
    ax += v.x; ay += v.y; az += v.z;
  }
  float d = dinv[n];
  xt[n] = make_float4(ax * d, ay * d, az * d, 0.f);
}

// bufA[n,c] = relu(BN(xt[n,:3] @ W0[:,c] + b[c])) * dinv[n]   (pre-scaled for next gather)
__global__ void k_mm3bn(const float4* __restrict__ xt, const float* __restrict__ W,
                        const float* __restrict__ b, const float* __restrict__ gam,
                        const float* __restrict__ bet, const float* __restrict__ rm,
                        const float* __restrict__ rv, const float* __restrict__ dinv,
                        float* __restrict__ out) {
  int t = blockIdx.x * 256 + threadIdx.x;
  int n = t >> 6, c = t & 63;
  if (n >= NN) return;
  float4 xv = xt[n];
  float acc = b[c];
  acc = fmaf(xv.x, W[c], acc);
  acc = fmaf(xv.y, W[64 + c], acc);
  acc = fmaf(xv.z, W[128 + c], acc);
  float sc = gam[c] * rsqrtf(rv[c] + EPS);
  float sh = bet[c] - rm[c] * sc;
  out[(size_t)n * 64 + c] = fmaxf(fmaf(acc, sc, sh), 0.f) * dinv[n];
}

// ---------- fused layer: gather(xs) -> *dinv -> @W + b -> BN -> ReLU [-> *dinv] ----------
// xs[n,:] = prev_feature[n,:] * dinv[n].  16 threads/node, float4 channels.
// agg exchange via LDS (padded 68 to kill 4-way bank conflicts), then each thread
// computes its 4 output channels (256 FMA) hidden under gather latency.
template <bool SCALE_OUT>
__global__ void k_layer(const float4* __restrict__ xs, const int* __restrict__ row,
                        const int* __restrict__ csr, const float* __restrict__ dinv,
                        const float* __restrict__ b, const float* __restrict__ gam,
                        const float* __restrict__ bet, const float* __restrict__ rm,
                        const float* __restrict__ rv, float4* __restrict__ out) {
  __shared__ float sh[16][68];
  int t = blockIdx.x * 256 + threadIdx.x;
  int n = t >> 4, sub = t & 15;
  int local = threadIdx.x >> 4;
  if (n >= NN) return;  // N = 100000 = 16*6250: blocks are always full, barrier-safe
  int s0 = row[n], s1 = row[n + 1];
  float4 a = xs[(size_t)n * 16 + sub];  // self-loop term (already * dinv[n])
  int i = s0;
  for (; i + 8 <= s1; i += 8) {
    int idx[8];
#pragma unroll
    for (int j = 0; j < 8; ++j) idx[j] = csr[i + j];
    float4 v[8];
#pragma unroll
    for (int j = 0; j < 8; ++j) v[j] = xs[(size_t)idx[j] * 16 + sub];
#pragma unroll
    for (int j = 0; j < 8; ++j) {
      a.x += v[j].x; a.y += v[j].y; a.z += v[j].z; a.w += v[j].w;
    }
  }
  for (; i < s1; ++i) {
    float4 v = xs[(size_t)csr[i] * 16 + sub];
    a.x += v.x; a.y += v.y; a.z += v.z; a.w += v.w;
  }
  float d = dinv[n];
  sh[local][sub * 4 + 0] = a.x * d;
  sh[local][sub * 4 + 1] = a.y * d;
  sh[local][sub * 4 + 2] = a.z * d;
  sh[local][sub * 4 + 3] = a.w * d;
  __syncthreads();
  // matmul: out[c] = sum_k agg[k] * W[k][c], c = sub*4..sub*4+3
  const float4* W4 = (const float4*)b;  // placeholder to keep types obvious; real W below
  (void)W4;
  const float4* Wv = (const float4*)gam;  // not used; see below
  (void)Wv;
  // (W passed via bet? no — use dedicated params)
  // -- actual matmul uses Wmat (passed through 'rm'? no) --
  // NOTE: W is passed as separate kernel arg below.
  out[0] = out[0];  // unreachable placeholder (replaced)
}

// Real fused layer kernel (explicit W argument).
template <bool SCALE_OUT>
__global__ void k_layer2(const float4* __restrict__ xs, const int* __restrict__ row,
                         const int* __restrict__ csr, const float* __restrict__ dinv,
                         const float* __restrict__ W, const float* __restrict__ b,
                         const float* __restrict__ gam, const float* __restrict__ bet,
                         const float* __restrict__ rm, const float* __restrict__ rv,
                         float4* __restrict__ out) {
  __shared__ float sh[16][68];
  int t = blockIdx.x * 256 + threadIdx.x;
  int n = t >> 4, sub = t & 15;
  int local = threadIdx.x >> 4;
  if (n >= NN) return;  // N = 16*6250 exactly: no partial blocks
  int s0 = row[n], s1 = row[n + 1];
  float4 a = xs[(size_t)n * 16 + sub];
  int i = s0;
  for (; i + 8 <= s1; i += 8) {
    int idx[8];
#pragma unroll
    for (int j = 0; j < 8; ++j) idx[j] = csr[i + j];
    float4 v[8];
#pragma unroll
    for (int j = 0; j < 8; ++j) v[j] = xs[(size_t)idx[j] * 16 + sub];
#pragma unroll
    for (int j = 0; j < 8; ++j) {
      a.x += v[j].x; a.y += v[j].y; a.z += v[j].z; a.w += v[j].w;
    }
  }
  for (; i < s1; ++i) {
    float4 v = xs[(size_t)csr[i] * 16 + sub];
    a.x += v.x; a.y += v.y; a.z += v.z; a.w += v.w;
  }
  float d = dinv[n];
  sh[local][sub * 4 + 0] = a.x * d;
  sh[local][sub * 4 + 1] = a.y * d;
  sh[local][sub * 4 + 2] = a.z * d;
  sh[local][sub * 4 + 3] = a.w * d;
  __syncthreads();
  const float4* W4 = (const float4*)W;
  float4 bb = ((const float4*)b)[sub];
  float4 acc = bb;
#pragma unroll 8
  for (int k = 0; k < 64; ++k) {
    float xv = sh[local][k];
    float4 w = W4[k * 16 + sub];
    acc.x = fmaf(xv, w.x, acc.x);
    acc.y = fmaf(xv, w.y, acc.y);
    acc.z = fmaf(xv, w.z, acc.z);
    acc.w = fmaf(xv, w.w, acc.w);
  }
  float4 g4 = ((const float4*)gam)[sub];
  float4 be4 = ((const float4*)bet)[sub];
  float4 rm4 = ((const float4*)rm)[sub];
  float4 rv4 = ((const float4*)rv)[sub];
  float scx = g4.x * rsqrtf(rv4.x + EPS), shx = be4.x - rm4.x * scx;
  float scy = g4.y * rsqrtf(rv4.y + EPS), shy = be4.y - rm4.y * scy;
  float scz = g4.z * rsqrtf(rv4.z + EPS), shz = be4.z - rm4.z * scz;
  float scw = g4.w * rsqrtf(rv4.w + EPS), shw = be4.w - rm4.w * scw;
  float4 o;
  o.x = fmaxf(fmaf(acc.x, scx, shx), 0.f);
  o.y = fmaxf(fmaf(acc.y, scy, shy), 0.f);
  o.z = fmaxf(fmaf(acc.z, scz, shz), 0.f);
  o.w = fmaxf(fmaf(acc.w, scw, shw), 0.f);
  if (SCALE_OUT) { o.x *= d; o.y *= d; o.z *= d; o.w *= d; }
  out[(size_t)n * 16 + sub] = o;
}

// ---------- fused pooling + MLP: one block per graph, no atomics ----------
__device__ __forceinline__ int lower_bound(const int* __restrict__ b, int target) {
  int lo = 0, hi = NN;
  while (lo < hi) {
    int m = (lo + hi) >> 1;
    if (b[m] < target) lo = m + 1; else hi = m;
  }
  return lo;
}

__global__ void k_poolmlp(const float* __restrict__ feat, const int* __restrict__ bidx,
                          const float* __restrict__ mW1, const float* __restrict__ mb1,
                          const float* __restrict__ mW2, const float* __restrict__ mb2,
                          const float* __restrict__ mW3, const float* __restrict__ mb3,
                          float* __restrict__ out) {
  __shared__ float ssum[4][64], smax[4][64], xg[128], h1[32], h2[16];
  int g = blockIdx.x, t = threadIdx.x;  // 256 threads
  int c = t & 63, q = t >> 6;
  int lo = lower_bound(bidx, g);
  int hi = lower_bound(bidx, g + 1);
  float s = 0.f, m = 0.f;  // feat >= 0 post-ReLU; empty graph -> 0 matches reference
  for (int i = lo + q; i < hi; i += 4) {
    float v = feat[(size_t)i * 64 + c];
    s += v;
    m = fmaxf(m, v);
  }
  ssum[q][c] = s;
  smax[q][c] = m;
  __syncthreads();
  if (q == 0) {
    float cs = ssum[0][c] + ssum[1][c] + ssum[2][c] + ssum[3][c];
    float cm = fmaxf(fmaxf(smax[0][c], smax[1][c]), fmaxf(smax[2][c], smax[3][c]));
    float cnt = fmaxf((float)(hi - lo), 1.0f);
    xg[c] = cs / cnt;
    xg[64 + c] = cm;
  }
  __syncthreads();
  if (t < 32) {
    float a = mb1[t];
    for (int k = 0; k < 128; ++k) a = fmaf(xg[k], mW1[k * 32 + t], a);
    h1[t] = fmaxf(a, 0.f);
  }
  __syncthreads();
  if (t < 16) {
    float a = mb2[t];
    for (int k = 0; k < 32; ++k) a = fmaf(h1[k], mW2[k * 16 + t], a);
    h2[t] = fmaxf(a, 0.f);
  }
  __syncthreads();
  if (t == 0) {
    float a = mb3[0];
    for (int k = 0; k < 16; ++k) a = fmaf(h2[k], mW3[k], a);
    out[g] = a;
  }
}

extern "C" void kernel_launch(void* const* d_in, const int* in_sizes, int n_in,
                              void* d_out, int out_size, void* d_ws, size_t ws_size,
                              hipStream_t stream) {
  const float* x = (const float*)d_in[0];
  const int* ei = (const int*)d_in[1];
  const int* bidx = (const int*)d_in[2];
  const float *W[3], *b[3], *gam[3], *bet[3], *rm[3], *rv[3];
  for (int l = 0; l < 3; ++l) {
    W[l] = (const float*)d_in[3 + 6 * l];
    b[l] = (const float*)d_in[4 + 6 * l];
    gam[l] = (const float*)d_in[5 + 6 * l];
    bet[l] = (const float*)d_in[6 + 6 * l];
    rm[l] = (const float*)d_in[7 + 6 * l];
    rv[l] = (const float*)d_in[8 + 6 * l];
  }
  const float* mW1 = (const float*)d_in[21];
  const float* mb1 = (const float*)d_in[22];
  const float* mW2 = (const float*)d_in[23];
  const float* mb2 = (const float*)d_in[24];
  const float* mW3 = (const float*)d_in[25];
  const float* mb3 = (const float*)d_in[26];
  float* out = (float*)d_out;

  char* ws = (char*)d_ws;
  size_t off = 0;
  auto alloc = [&](size_t bytes) {
    void* p = ws + off;
    off = (off + bytes + 1023) & ~(size_t)1023;
    return p;
  };
  float* dinv = (float*)alloc(NN * 4);
  int* row = (int*)alloc((NN + 1) * 4);
  int* fill = (int*)alloc(NN * 4);
  int* csr = (int*)alloc((size_t)EE * 4);
  int* sums = (int*)alloc(512 * 4);
  float4* xd = (float4*)alloc((size_t)NN * 16);
  float4* xt = (float4*)alloc((size_t)NN * 16);
  float* bufA = (float*)alloc((size_t)NN * 64 * 4);
  float* bufB = (float*)alloc((size_t)NN * 64 * 4);

  hipMemsetAsync(fill, 0, NN * 4, stream);

  int eb = (EE + 255) / 256;
  int nb = (NN + 255) / 256;
  int nb16 = (NN * 16 + 255) / 256;
  int nb64 = (NN * 64 + 255) / 256;

  // graph structure (once, reused for all 3 layers)
  k_hist<<<eb, 256, 0, stream>>>(ei, fill);
  k_dinv<<<nb, 256, 0, stream>>>(fill, dinv);
  k_scan1<<<SCAN_BLOCKS, 256, 0, stream>>>(fill, row, sums);
  k_scan2<<<1, 512, 0, stream>>>(sums);
  k_scan3<<<nb, 256, 0, stream>>>(row, sums, fill);
  k_scatter<<<eb, 256, 0, stream>>>(ei, fill, csr);

  // layer 0: aggregate 3-ch input first, matmul+BN+ReLU, pre-scale by dinv
  k_predinv<<<nb, 256, 0, stream>>>(x, dinv, xd);
  k_agg3<<<nb, 256, 0, stream>>>(xd, row, csr, dinv, xt);
  k_mm3bn<<<nb64, 256, 0, stream>>>(xt, W[0], b[0], gam[0], bet[0], rm[0], rv[0], dinv, bufA);
  // layer 1: fused gather + matmul + BN + ReLU, output pre-scaled for layer-2 gather
  k_layer2<true><<<nb16, 256, 0, stream>>>((const float4*)bufA, row, csr, dinv, W[1], b[1],
                                           gam[1], bet[1], rm[1], rv[1], (float4*)bufB);
  // layer 2: fused, unscaled output (final features)
  k_layer2<false><<<nb16, 256, 0, stream>>>((const float4*)bufB, row, csr, dinv, W[2], b[2],
                                            gam[2], bet[2], rm[2], rv[2], (float4*)bufA);
  // pooling (segmented, batch_idx sorted, no atomics) + graph MLP, one block/graph
  k_poolmlp<<<GG, 256, 0, stream>>>(bufA, bidx, mW1, mb1, mW2, mb2, mW3, mb3, out);
}

// Round 4
// 497.235 us; speedup vs baseline: 2.7348x; 1.1188x over previous
//
#include <hip/hip_runtime.h>

#define NN 100000
#define EE 1600000
#define GG 256
#define EPS 1e-5f
#define SCAN_BLOCKS ((NN + 255) / 256)  // 391
#define BSH 9                            // 512 dst nodes per bucket
#define KB ((NN + 511) >> 9)             // 196 buckets
#define EPB 4096                         // edges per block in passA/passB
#define EBLK ((EE + EPB - 1) / EPB)      // 391 blocks

// ---------- graph structure ----------
__global__ void k_hist(const int* __restrict__ ei, int* __restrict__ deg) {
  int e = blockIdx.x * 256 + threadIdx.x;
  if (e < EE) atomicAdd(&deg[ei[EE + e]], 1);
}

__global__ void k_dinv(const int* __restrict__ deg, float* __restrict__ dinv) {
  int n = blockIdx.x * 256 + threadIdx.x;
  if (n < NN) dinv[n] = rsqrtf((float)deg[n] + 1.0f);
}

__global__ void k_scan1(const int* __restrict__ deg, int* __restrict__ row,
                        int* __restrict__ sums) {
  __shared__ int sh[256];
  int tid = threadIdx.x;
  int i = blockIdx.x * 256 + tid;
  int v = (i < NN) ? deg[i] : 0;
  sh[tid] = v;
  __syncthreads();
  for (int off = 1; off < 256; off <<= 1) {
    int add = (tid >= off) ? sh[tid - off] : 0;
    __syncthreads();
    sh[tid] += add;
    __syncthreads();
  }
  if (i < NN) row[i] = sh[tid] - v;
  if (tid == 255) sums[blockIdx.x] = sh[255];
}

__global__ void k_scan2(int* __restrict__ sums) {  // 1 block, 512 threads
  __shared__ int sh[512];
  int t = threadIdx.x;
  int v = (t < SCAN_BLOCKS) ? sums[t] : 0;
  sh[t] = v;
  __syncthreads();
  for (int off = 1; off < 512; off <<= 1) {
    int add = (t >= off) ? sh[t - off] : 0;
    __syncthreads();
    sh[t] += add;
    __syncthreads();
  }
  if (t < SCAN_BLOCKS) sums[t] = sh[t] - v;
}

__global__ void k_scan3(int* __restrict__ row, const int* __restrict__ sums,
                        int* __restrict__ fill) {
  int i = blockIdx.x * 256 + threadIdx.x;
  if (i < NN) {
    int r = row[i] + sums[i >> 8];
    row[i] = r;
    fill[i] = r;
  }
  if (i == 0) row[NN] = EE;
}

// gfill[b] = csr base offset of bucket b (free from row since csr is dst-ordered)
__global__ void k_ginit(const int* __restrict__ row, int* __restrict__ gfill) {
  int b = blockIdx.x * 256 + threadIdx.x;
  if (b < KB) gfill[b] = row[b << BSH];
}

// pass A: bucket the (src,dst) pairs by dst>>9 into tmp (dense, bucket-ordered)
__global__ void k_passA(const int* __restrict__ ei, int* __restrict__ gfill,
                        int2* __restrict__ tmp) {
  __shared__ int cnt[KB], cur[KB], base[KB];
  int t = threadIdx.x;
  for (int b = t; b < KB; b += 256) { cnt[b] = 0; cur[b] = 0; }
  __syncthreads();
  int e0 = blockIdx.x * EPB;
  int myb[16];
#pragma unroll
  for (int j = 0; j < 16; ++j) {
    int e = e0 + j * 256 + t;
    int bb = -1;
    if (e < EE) bb = ei[EE + e] >> BSH;
    myb[j] = bb;
    if (bb >= 0) atomicAdd(&cnt[bb], 1);
  }
  __syncthreads();
  for (int b = t; b < KB; b += 256)
    if (cnt[b] > 0) base[b] = atomicAdd(&gfill[b], cnt[b]);
  __syncthreads();
#pragma unroll
  for (int j = 0; j < 16; ++j) {
    int e = e0 + j * 256 + t;
    int bb = myb[j];
    if (bb >= 0) {
      int slot = base[bb] + atomicAdd(&cur[bb], 1);
      tmp[slot] = make_int2(ei[e], ei[EE + e]);
    }
  }
}

// pass B: within-bucket scatter to exact csr slots (writes stay in a hot L2 window)
__global__ void k_passB(const int2* __restrict__ tmp, int* __restrict__ fill,
                        int* __restrict__ csr) {
  int e0 = blockIdx.x * EPB;
  int t = threadIdx.x;
#pragma unroll
  for (int j = 0; j < 16; ++j) {
    int i = e0 + j * 256 + t;
    if (i < EE) {
      int2 e = tmp[i];
      int slot = atomicAdd(&fill[e.y], 1);
      csr[slot] = e.x;
    }
  }
}

// ---------- layer 0 (3-channel, agg-before-matmul) ----------
__global__ void k_predinv(const float* __restrict__ x, const float* __restrict__ dinv,
                          float4* __restrict__ xd) {
  int n = blockIdx.x * 256 + threadIdx.x;
  if (n >= NN) return;
  float d = dinv[n];
  xd[n] = make_float4(x[n * 3] * d, x[n * 3 + 1] * d, x[n * 3 + 2] * d, 0.f);
}

__global__ void k_agg3(const float4* __restrict__ xd, const int* __restrict__ row,
                       const int* __restrict__ csr, const float* __restrict__ dinv,
                       float4* __restrict__ xt) {
  int n = blockIdx.x * 256 + threadIdx.x;
  if (n >= NN) return;
  int s0 = row[n], s1 = row[n + 1];
  float4 a = xd[n];
  float ax = a.x, ay = a.y, az = a.z;
  int i = s0;
  for (; i + 8 <= s1; i += 8) {
    int idx[8];
#pragma unroll
    for (int j = 0; j < 8; ++j) idx[j] = csr[i + j];
    float4 v[8];
#pragma unroll
    for (int j = 0; j < 8; ++j) v[j] = xd[idx[j]];
#pragma unroll
    for (int j = 0; j < 8; ++j) { ax += v[j].x; ay += v[j].y; az += v[j].z; }
  }
  for (; i < s1; ++i) {
    float4 v = xd[csr[i]];
    ax += v.x; ay += v.y; az += v.z;
  }
  float d = dinv[n];
  xt[n] = make_float4(ax * d, ay * d, az * d, 0.f);
}

// bufA[n,c] = relu(BN(xt[n,:3] @ W0[:,c] + b[c])) * dinv[n]   (pre-scaled for next gather)
__global__ void k_mm3bn(const float4* __restrict__ xt, const float* __restrict__ W,
                        const float* __restrict__ b, const float* __restrict__ gam,
                        const float* __restrict__ bet, const float* __restrict__ rm,
                        const float* __restrict__ rv, const float* __restrict__ dinv,
                        float* __restrict__ out) {
  int t = blockIdx.x * 256 + threadIdx.x;
  int n = t >> 6, c = t & 63;
  if (n >= NN) return;
  float4 xv = xt[n];
  float acc = b[c];
  acc = fmaf(xv.x, W[c], acc);
  acc = fmaf(xv.y, W[64 + c], acc);
  acc = fmaf(xv.z, W[128 + c], acc);
  float sc = gam[c] * rsqrtf(rv[c] + EPS);
  float sh = bet[c] - rm[c] * sc;
  out[(size_t)n * 64 + c] = fmaxf(fmaf(acc, sc, sh), 0.f) * dinv[n];
}

// ---------- fused layer: gather(xs) -> *dinv -> @W + b -> BN -> ReLU [-> *dinv] ----------
template <bool SCALE_OUT>
__global__ void k_layer2(const float4* __restrict__ xs, const int* __restrict__ row,
                         const int* __restrict__ csr, const float* __restrict__ dinv,
                         const float* __restrict__ W, const float* __restrict__ b,
                         const float* __restrict__ gam, const float* __restrict__ bet,
                         const float* __restrict__ rm, const float* __restrict__ rv,
                         float4* __restrict__ out) {
  __shared__ float sh[16][68];
  int t = blockIdx.x * 256 + threadIdx.x;
  int n = t >> 4, sub = t & 15;
  int local = threadIdx.x >> 4;
  if (n >= NN) return;  // N = 16*6250 exactly: no partial blocks, barrier-safe
  int s0 = row[n], s1 = row[n + 1];
  float4 a = xs[(size_t)n * 16 + sub];
  int i = s0;
  for (; i + 8 <= s1; i += 8) {
    int idx[8];
#pragma unroll
    for (int j = 0; j < 8; ++j) idx[j] = csr[i + j];
    float4 v[8];
#pragma unroll
    for (int j = 0; j < 8; ++j) v[j] = xs[(size_t)idx[j] * 16 + sub];
#pragma unroll
    for (int j = 0; j < 8; ++j) {
      a.x += v[j].x; a.y += v[j].y; a.z += v[j].z; a.w += v[j].w;
    }
  }
  for (; i < s1; ++i) {
    float4 v = xs[(size_t)csr[i] * 16 + sub];
    a.x += v.x; a.y += v.y; a.z += v.z; a.w += v.w;
  }
  float d = dinv[n];
  sh[local][sub * 4 + 0] = a.x * d;
  sh[local][sub * 4 + 1] = a.y * d;
  sh[local][sub * 4 + 2] = a.z * d;
  sh[local][sub * 4 + 3] = a.w * d;
  __syncthreads();
  const float4* W4 = (const float4*)W;
  float4 acc = ((const float4*)b)[sub];
#pragma unroll 8
  for (int k = 0; k < 64; ++k) {
    float xv = sh[local][k];
    float4 w = W4[k * 16 + sub];
    acc.x = fmaf(xv, w.x, acc.x);
    acc.y = fmaf(xv, w.y, acc.y);
    acc.z = fmaf(xv, w.z, acc.z);
    acc.w = fmaf(xv, w.w, acc.w);
  }
  float4 g4 = ((const float4*)gam)[sub];
  float4 be4 = ((const float4*)bet)[sub];
  float4 rm4 = ((const float4*)rm)[sub];
  float4 rv4 = ((const float4*)rv)[sub];
  float scx = g4.x * rsqrtf(rv4.x + EPS), shx = be4.x - rm4.x * scx;
  float scy = g4.y * rsqrtf(rv4.y + EPS), shy = be4.y - rm4.y * scy;
  float scz = g4.z * rsqrtf(rv4.z + EPS), shz = be4.z - rm4.z * scz;
  float scw = g4.w * rsqrtf(rv4.w + EPS), shw = be4.w - rm4.w * scw;
  float4 o;
  o.x = fmaxf(fmaf(acc.x, scx, shx), 0.f);
  o.y = fmaxf(fmaf(acc.y, scy, shy), 0.f);
  o.z = fmaxf(fmaf(acc.z, scz, shz), 0.f);
  o.w = fmaxf(fmaf(acc.w, scw, shw), 0.f);
  if (SCALE_OUT) { o.x *= d; o.y *= d; o.z *= d; o.w *= d; }
  out[(size_t)n * 16 + sub] = o;
}

// ---------- fused pooling + MLP: one block per graph, no atomics ----------
__device__ __forceinline__ int lower_bound(const int* __restrict__ b, int target) {
  int lo = 0, hi = NN;
  while (lo < hi) {
    int m = (lo + hi) >> 1;
    if (b[m] < target) lo = m + 1; else hi = m;
  }
  return lo;
}

__global__ void k_poolmlp(const float* __restrict__ feat, const int* __restrict__ bidx,
                          const float* __restrict__ mW1, const float* __restrict__ mb1,
                          const float* __restrict__ mW2, const float* __restrict__ mb2,
                          const float* __restrict__ mW3, const float* __restrict__ mb3,
                          float* __restrict__ out) {
  __shared__ float ssum[4][64], smax[4][64], xg[128], h1[32], h2[16];
  int g = blockIdx.x, t = threadIdx.x;  // 256 threads
  int c = t & 63, q = t >> 6;
  int lo = lower_bound(bidx, g);
  int hi = lower_bound(bidx, g + 1);
  float s = 0.f, m = 0.f;  // feat >= 0 post-ReLU; empty graph -> 0 matches reference
  for (int i = lo + q; i < hi; i += 4) {
    float v = feat[(size_t)i * 64 + c];
    s += v;
    m = fmaxf(m, v);
  }
  ssum[q][c] = s;
  smax[q][c] = m;
  __syncthreads();
  if (q == 0) {
    float cs = ssum[0][c] + ssum[1][c] + ssum[2][c] + ssum[3][c];
    float cm = fmaxf(fmaxf(smax[0][c], smax[1][c]), fmaxf(smax[2][c], smax[3][c]));
    float cnt = fmaxf((float)(hi - lo), 1.0f);
    xg[c] = cs / cnt;
    xg[64 + c] = cm;
  }
  __syncthreads();
  if (t < 32) {
    float a = mb1[t];
    for (int k = 0; k < 128; ++k) a = fmaf(xg[k], mW1[k * 32 + t], a);
    h1[t] = fmaxf(a, 0.f);
  }
  __syncthreads();
  if (t < 16) {
    float a = mb2[t];
    for (int k = 0; k < 32; ++k) a = fmaf(h1[k], mW2[k * 16 + t], a);
    h2[t] = fmaxf(a, 0.f);
  }
  __syncthreads();
  if (t == 0) {
    float a = mb3[0];
    for (int k = 0; k < 16; ++k) a = fmaf(h2[k], mW3[k], a);
    out[g] = a;
  }
}

extern "C" void kernel_launch(void* const* d_in, const int* in_sizes, int n_in,
                              void* d_out, int out_size, void* d_ws, size_t ws_size,
                              hipStream_t stream) {
  const float* x = (const float*)d_in[0];
  const int* ei = (const int*)d_in[1];
  const int* bidx = (const int*)d_in[2];
  const float *W[3], *b[3], *gam[3], *bet[3], *rm[3], *rv[3];
  for (int l = 0; l < 3; ++l) {
    W[l] = (const float*)d_in[3 + 6 * l];
    b[l] = (const float*)d_in[4 + 6 * l];
    gam[l] = (const float*)d_in[5 + 6 * l];
    bet[l] = (const float*)d_in[6 + 6 * l];
    rm[l] = (const float*)d_in[7 + 6 * l];
    rv[l] = (const float*)d_in[8 + 6 * l];
  }
  const float* mW1 = (const float*)d_in[21];
  const float* mb1 = (const float*)d_in[22];
  const float* mW2 = (const float*)d_in[23];
  const float* mb2 = (const float*)d_in[24];
  const float* mW3 = (const float*)d_in[25];
  const float* mb3 = (const float*)d_in[26];
  float* out = (float*)d_out;

  char* ws = (char*)d_ws;
  size_t off = 0;
  auto alloc = [&](size_t bytes) {
    void* p = ws + off;
    off = (off + bytes + 1023) & ~(size_t)1023;
    return p;
  };
  float* dinv = (float*)alloc(NN * 4);
  int* row = (int*)alloc((NN + 1) * 4);
  int* fill = (int*)alloc(NN * 4);
  int* csr = (int*)alloc((size_t)EE * 4);
  int* sums = (int*)alloc(512 * 4);
  int* gfill = (int*)alloc(KB * 4);
  float4* xd = (float4*)alloc((size_t)NN * 16);
  float4* xt = (float4*)alloc((size_t)NN * 16);
  float* bufA = (float*)alloc((size_t)NN * 64 * 4);
  float* bufB = (float*)alloc((size_t)NN * 64 * 4);
  int2* tmp = (int2*)bufA;  // 12.8 MB alias; bufA first written later by k_mm3bn

  hipMemsetAsync(fill, 0, NN * 4, stream);

  int eb = (EE + 255) / 256;
  int nb = (NN + 255) / 256;
  int nb16 = (NN * 16 + 255) / 256;
  int nb64 = (NN * 64 + 255) / 256;

  // graph structure (once, reused for all 3 layers)
  k_hist<<<eb, 256, 0, stream>>>(ei, fill);
  k_dinv<<<nb, 256, 0, stream>>>(fill, dinv);
  k_scan1<<<SCAN_BLOCKS, 256, 0, stream>>>(fill, row, sums);
  k_scan2<<<1, 512, 0, stream>>>(sums);
  k_scan3<<<nb, 256, 0, stream>>>(row, sums, fill);
  // bucketed CSR build (2 dense passes instead of 1 write-amplified scatter)
  k_ginit<<<1, 256, 0, stream>>>(row, gfill);
  k_passA<<<EBLK, 256, 0, stream>>>(ei, gfill, tmp);
  k_passB<<<EBLK, 256, 0, stream>>>(tmp, fill, csr);

  // layer 0: aggregate 3-ch input first, matmul+BN+ReLU, pre-scale by dinv
  k_predinv<<<nb, 256, 0, stream>>>(x, dinv, xd);
  k_agg3<<<nb, 256, 0, stream>>>(xd, row, csr, dinv, xt);
  k_mm3bn<<<nb64, 256, 0, stream>>>(xt, W[0], b[0], gam[0], bet[0], rm[0], rv[0], dinv, bufA);
  // layer 1: fused gather + matmul + BN + ReLU, output pre-scaled for layer-2 gather
  k_layer2<true><<<nb16, 256, 0, stream>>>((const float4*)bufA, row, csr, dinv, W[1], b[1],
                                           gam[1], bet[1], rm[1], rv[1], (float4*)bufB);
  // layer 2: fused, unscaled output (final features)
  k_layer2<false><<<nb16, 256, 0, stream>>>((const float4*)bufB, row, csr, dinv, W[2], b[2],
                                            gam[2], bet[2], rm[2], rv[2], (float4*)bufA);
  // pooling (segmented, batch_idx sorted, no atomics) + graph MLP
  k_poolmlp<<<GG, 256, 0, stream>>>(bufA, bidx, mW1, mb1, mW2, mb2, mW3, mb3, out);
}